// Round 11
// baseline (106.871 us; speedup 1.0000x reference)
//
#include <hip/hip_runtime.h>
#include <math.h>

// Neural-ODE RK45 — round 11: 16 lanes/element, zero-DS, K-split by half,
// 3 resident waves/SIMD.
// r10 evidence: zero-DS == LDS-broadcast (both ~31 us) -> cross-lane pipe is
// not the wall; issue density ~43% at 2 resident waves is. This round cuts
// the footprint (w2 slice 128 -> 64 VGPRs) so 3 waves/SIMD fit, and cuts
// instr/eval ~110 -> ~69:
//  - lane m owns output cols {2b,2b+1}, b = m<8 ? m : 23-m (pairs under
//    xor15). Half p (=m>>3) lanes own h1 cols 16p..16p+15.
//  - K-split: lane accumulates its half's 16 rows for its 2 cols (accMine,
//    bias folded in) and its xor15-partner's 2 cols (accOther).
//  - in-half gather of 16 h1: 3-stage involution DPP butterfly
//    (xor1=0xB1, xor2=0x4E, xor7=0x141), arrival perm P={0,1,2,3,7,6,5,4}
//    folded into the w2 register load order.
//  - cross-half exchange + final allreduce use xor15 (0x140, row_mirror).
// All cross-lane on the VALU pipe; no DS, no lgkmcnt in the loop.
// FSAL (k1 = accept?k7:k1, bitwise), pinning, exp2/log2 controller kept.
// 262144 threads = 4096 waves = 4/SIMD launched, 3 resident -> backfill.

#define MAXS 96

typedef float v2f __attribute__((ext_vector_type(2)));

static __device__ __forceinline__ v2f splat(float s){ v2f v; v.x=s; v.y=s; return v; }
static __device__ __forceinline__ v2f vfma(v2f a, v2f b, v2f c){ return __builtin_elementwise_fma(a,b,c); }
static __device__ __forceinline__ v2f vrelu(v2f a){ return __builtin_elementwise_max(a, splat(0.0f)); }

template<int CTRL>
static __device__ __forceinline__ float dppf(float x){
    return __int_as_float(__builtin_amdgcn_update_dpp(0, __float_as_int(x), CTRL, 0xF, 0xF, false));
}
template<int CTRL>
static __device__ __forceinline__ v2f dppv(v2f a){
    v2f r; r.x = dppf<CTRL>(a.x); r.y = dppf<CTRL>(a.y); return r;
}
// 16-lane all-reduce: xor1, xor2, xor7, xor15 — all involutions, all VALU.
static __device__ __forceinline__ v2f dpp_allreduce16(v2f p){
    p += dppv<0xB1>(p);    // quad_perm xor1
    p += dppv<0x4E>(p);    // quad_perm xor2
    p += dppv<0x141>(p);   // row_half_mirror = xor7 (in 8)
    p += dppv<0x140>(p);   // row_mirror = xor15 (in 16)
    return p;
}

__global__ __launch_bounds__(256, 3) void node_kernel(
    const float* __restrict__ x, const float* __restrict__ samples,
    const float* __restrict__ w1, const float* __restrict__ b1,
    const float* __restrict__ w2, const float* __restrict__ b2,
    const float* __restrict__ w3, const float* __restrict__ b3,
    const float* __restrict__ fcw, const float* __restrict__ fcb,
    float* __restrict__ out, int n)
{
    const int tid  = blockIdx.x * blockDim.x + threadIdx.x;
    const int elem = tid >> 4;
    const int m    = tid & 15;               // lane in 16-lane group
    if (elem >= n) return;
    const int p = m >> 3;                    // half (0/1)
    const int i = m & 7;                     // lane within half
    const int b = (m < 8) ? m : (23 - m);    // my col block (xor15-paired)
    const int ob = (m < 8) ? (8 + m) : (15 - m); // partner's col block

    // ---- weight slices (loaded once, pinned) ----
    const v2f* w2v = (const v2f*)w2;         // (32,32): w2v[r*16 + c/2]
    // Butterfly arrival perm: g[j] comes from in-half lane i ^ P[j].
    const int P[8] = {0,1,2,3,7,6,5,4};
    v2f w2m[16], w2o[16];                    // [2j],[2j+1] = rows 2bb, 2bb+1
#pragma unroll
    for (int j = 0; j < 8; ++j) {
        int lo = 8*p + (i ^ P[j]);           // owner lane of g[j]
        int bb = (p == 0) ? lo : (23 - lo);  // owner's col block = h1 rows
        w2m[2*j+0] = w2v[(2*bb    ) * 16 + b];
        w2m[2*j+1] = w2v[(2*bb + 1) * 16 + b];
        w2o[2*j+0] = w2v[(2*bb    ) * 16 + ob];
        w2o[2*j+1] = w2v[(2*bb + 1) * 16 + ob];
    }
    const v2f* w1v = (const v2f*)w1;         // (3,32)
    v2f w1p0 = w1v[0*16 + b], w1p1 = w1v[1*16 + b], w1p2 = w1v[2*16 + b];
    v2f b1p  = ((const v2f*)b1)[b];
    v2f b2p  = ((const v2f*)b2)[b];          // bias for my cols (added once)
    const v2f* w3v = (const v2f*)w3;         // row r -> (w3[r][0], w3[r][1])
    v2f w3r0 = w3v[2*b], w3r1 = w3v[2*b + 1];
    v2f b3c; b3c.x = b3[0]; b3c.y = b3[1];

#pragma unroll
    for (int k = 0; k < 16; ++k) { asm volatile("" : "+v"(w2m[k]), "+v"(w2o[k])); }
    asm volatile("" : "+v"(w1p0), "+v"(w1p1), "+v"(w1p2), "+v"(b1p), "+v"(b2p));
    asm volatile("" : "+v"(w3r0), "+v"(w3r1));

    v2f y = ((const v2f*)x)[elem];           // ODE state (y0, y1)
    float T = fminf(samples[elem], 50.0f);
    float t = 0.0f;
    float h = 0.05f;

    // f(t, y): ~69 instr, all cross-lane via DPP (zero DS).
    auto f_eval = [&](float tt, v2f z) -> v2f {
        // layer 1: my 2 cols (1 pk chain)
        v2f hv = vrelu(vfma(splat(tt), w1p0, vfma(splat(z.x), w1p1,
                       vfma(splat(z.y), w1p2, b1p))));

        // in-half butterfly all-gather: 8 pk pairs = my half's 16 h1
        v2f g0 = hv;
        v2f g1 = dppv<0xB1>(g0);
        v2f g2 = dppv<0x4E>(g0), g3 = dppv<0x4E>(g1);
        v2f g4 = dppv<0x141>(g0), g5 = dppv<0x141>(g1);
        v2f g6 = dppv<0x141>(g2), g7 = dppv<0x141>(g3);

        // layer 2, K-split: my half's 16 rows x (my 2 cols + partner's 2)
        v2f am = b2p, ao = splat(0.0f);
#define L2(j, gj) \
        am = vfma(splat((gj).x), w2m[2*(j)+0], am); \
        am = vfma(splat((gj).y), w2m[2*(j)+1], am); \
        ao = vfma(splat((gj).x), w2o[2*(j)+0], ao); \
        ao = vfma(splat((gj).y), w2o[2*(j)+1], ao);
        L2(0,g0) L2(1,g1) L2(2,g2) L2(3,g3) L2(4,g4) L2(5,g5) L2(6,g6) L2(7,g7)
#undef L2

        // cross-half exchange: partner's ao (xor15) completes my cols
        v2f h2 = vrelu(am + dppv<0x140>(ao));

        // layer 3: my 2 rows -> 2 outputs, then 16-lane all-reduce
        v2f q = vfma(splat(h2.x), w3r0, splat(h2.y) * w3r1);
        q = dpp_allreduce16(q);
        return q + b3c;
    };

    // FSAL: initial k1; thereafter k1 = accept ? k7 : k1 (bitwise exact).
    v2f k1 = f_eval(0.0f, y);

    for (int s = 0; s < MAXS; ++s) {
        float rem = T - t;
        if (!(rem > 1e-8f)) break;           // state frozen from here on
        float hs = fminf(h, rem);
        v2f hb = splat(hs);

        v2f k2 = f_eval(t + hs * 0.2f, vfma(hb, splat(0.2f) * k1, y));
        v2f k3 = f_eval(t + hs * 0.3f,
                 vfma(hb, vfma(splat((float)(3.0/40.0)), k1, splat((float)(9.0/40.0)) * k2), y));
        v2f k4 = f_eval(t + hs * 0.8f,
                 vfma(hb, vfma(splat((float)(44.0/45.0)), k1,
                          vfma(splat((float)(-56.0/15.0)), k2, splat((float)(32.0/9.0)) * k3)), y));
        v2f k5 = f_eval(t + hs * (float)(8.0/9.0),
                 vfma(hb, vfma(splat((float)(19372.0/6561.0)), k1,
                          vfma(splat((float)(-25360.0/2187.0)), k2,
                          vfma(splat((float)(64448.0/6561.0)), k3,
                               splat((float)(-212.0/729.0)) * k4))), y));
        v2f k6 = f_eval(t + hs,
                 vfma(hb, vfma(splat((float)(9017.0/3168.0)), k1,
                          vfma(splat((float)(-355.0/33.0)), k2,
                          vfma(splat((float)(46732.0/5247.0)), k3,
                          vfma(splat((float)(49.0/176.0)), k4,
                               splat((float)(-5103.0/18656.0)) * k5)))), y));
        v2f y5 = vfma(hb, vfma(splat((float)(35.0/384.0)), k1,
                          vfma(splat((float)(500.0/1113.0)), k3,
                          vfma(splat((float)(125.0/192.0)), k4,
                          vfma(splat((float)(-2187.0/6784.0)), k5,
                               splat((float)(11.0/84.0)) * k6)))), y);
        v2f k7 = f_eval(t + hs, y5);

        v2f err = hb * vfma(splat((float)(71.0/57600.0)), k1,
                       vfma(splat((float)(-71.0/16695.0)), k3,
                       vfma(splat((float)(71.0/1920.0)), k4,
                       vfma(splat((float)(-17253.0/339200.0)), k5,
                       vfma(splat((float)(22.0/525.0)), k6,
                            splat((float)(-1.0/40.0)) * k7)))));

        v2f sc = vfma(splat(0.01f),
                 __builtin_elementwise_max(__builtin_elementwise_abs(y),
                                           __builtin_elementwise_abs(y5)), splat(0.01f));
        v2f r = err / sc;
        float en = sqrtf(0.5f * (r.x * r.x + r.y * r.y));

        float fac = fminf(fmaxf(0.9f * exp2f(-0.2f * log2f(fmaxf(en, 1e-10f))), 0.2f), 10.0f);

        bool accept = (en <= 1.0f);
        if (accept) { t += hs; y = y5; }
        k1 = accept ? k7 : k1;               // FSAL (exact)
        h = hs * fac;
    }

    // final head: y @ fc_w (2x10) + fc_b; all 16 lanes hold identical y.
    if (m < 10) {
        out[10 * elem + m] = fmaf(y.x, fcw[m], fmaf(y.y, fcw[10 + m], fcb[m]));
    }
}

extern "C" void kernel_launch(void* const* d_in, const int* in_sizes, int n_in,
                              void* d_out, int out_size, void* d_ws, size_t ws_size,
                              hipStream_t stream) {
    const float* x   = (const float*)d_in[0];
    const float* sm  = (const float*)d_in[1];
    const float* w1  = (const float*)d_in[2];
    const float* b1  = (const float*)d_in[3];
    const float* w2  = (const float*)d_in[4];
    const float* b2  = (const float*)d_in[5];
    const float* w3  = (const float*)d_in[6];
    const float* b3  = (const float*)d_in[7];
    const float* fcw = (const float*)d_in[8];
    const float* fcb = (const float*)d_in[9];
    // d_in[10..15] = enc_* : dead code in the reference, unused.
    float* out = (float*)d_out;

    int n = in_sizes[1];                        // B
    const int block = 256;
    long long threads = (long long)n * 16;      // 16 lanes per element
    int grid = (int)((threads + block - 1) / block);   // 1024 blocks
    node_kernel<<<grid, block, 0, stream>>>(x, sm, w1, b1, w2, b2, w3, b3,
                                            fcw, fcb, out, n);
}

// Round 12
// 100.613 us; speedup vs baseline: 1.0622x; 1.0622x over previous
//
#include <hip/hip_runtime.h>
#include <math.h>

// Neural-ODE RK45 — FINAL (revert to round-7 structure, the best-measured
// variant: 101.3 us total vs 102.6-114 for rounds 8-11).
// 8 lanes per element; lane m owns hidden cols [4m,4m+4) (w2 slice = 128
// VGPRs, pinned). Intra-quad h1 exchange via quad_perm DPP (VALU pipe);
// only the other quad's 16 floats cross LDS (1x ds_write_b128 + 4x
// broadcast ds_read_b128 = 80 B/lane/eval). 131072 threads = 2048 waves.
// FSAL (k1 = accept ? k7 : k1, bitwise exact), register-pinned weights,
// exp2/log2 step controller. Session evidence (rounds 7-11): DS-broadcast
// vs all-DPP vs K-split variants are interchangeable at a ~25-35 us kernel
// plateau (latency-bound serial RK45; residency capped by weight VGPRs);
// total dur_us is dominated by ~72-76 us of harness poison-fill overhead.

#define MAXS 96

typedef float v2f __attribute__((ext_vector_type(2)));

static __device__ __forceinline__ v2f splat(float s){ v2f v; v.x=s; v.y=s; return v; }
static __device__ __forceinline__ v2f vfma(v2f a, v2f b, v2f c){ return __builtin_elementwise_fma(a,b,c); }
static __device__ __forceinline__ v2f vrelu(v2f a){ return __builtin_elementwise_max(a, splat(0.0f)); }

template<int CTRL>
static __device__ __forceinline__ float dppf(float x){
    return __int_as_float(__builtin_amdgcn_update_dpp(0, __float_as_int(x), CTRL, 0xF, 0xF, false));
}
// 8-lane all-reduce: xor1 (0xB1), xor2 (0x4E), 8-lane mirror (0x141)
static __device__ __forceinline__ v2f dpp_allreduce8(v2f p){
    p.x += dppf<0xB1>(p.x);  p.y += dppf<0xB1>(p.y);
    p.x += dppf<0x4E>(p.x);  p.y += dppf<0x4E>(p.y);
    p.x += dppf<0x141>(p.x); p.y += dppf<0x141>(p.y);
    return p;
}

__global__ __launch_bounds__(256, 2) void node_kernel(
    const float* __restrict__ x, const float* __restrict__ samples,
    const float* __restrict__ w1, const float* __restrict__ b1,
    const float* __restrict__ w2, const float* __restrict__ b2,
    const float* __restrict__ w3, const float* __restrict__ b3,
    const float* __restrict__ fcw, const float* __restrict__ fcb,
    float* __restrict__ out, int n)
{
    const int tid  = blockIdx.x * blockDim.x + threadIdx.x;
    const int elem = tid >> 3;
    const int m    = tid & 7;            // lane in 8-lane group
    if (elem >= n) return;
    const int q = m >> 2;                // quad within group (0 or 1)

    // 32 groups/block, 36-float (144 B) slots: 16B-aligned, groups stagger
    // by 4 banks -> <=2-way aliasing on the broadcast b128 reads.
    __shared__ float lds[32 * 36];
    float* slot = &lds[(threadIdx.x >> 3) * 36];
    const int mineBase  = 16 * q;        // my quad's 16 cols
    const int otherBase = 16 - mineBase; // the other quad's 16 cols

    // ---- weight slices: lane owns cols [4m,4m+4) ----
    const float4* w2v4 = (const float4*)w2;   // (32,32): row i, col-quad m
    v2f w2mA[16], w2mB[16];   // rows mineBase+k  -> own col pair A={4m,4m+1}, B={4m+2,4m+3}
    v2f w2oA[16], w2oB[16];   // rows otherBase+k
#pragma unroll
    for (int k = 0; k < 16; ++k) {
        float4 rm = w2v4[(mineBase  + k) * 8 + m];
        float4 ro = w2v4[(otherBase + k) * 8 + m];
        w2mA[k].x = rm.x; w2mA[k].y = rm.y; w2mB[k].x = rm.z; w2mB[k].y = rm.w;
        w2oA[k].x = ro.x; w2oA[k].y = ro.y; w2oB[k].x = ro.z; w2oB[k].y = ro.w;
    }
    float4 w1f0 = ((const float4*)w1)[0 * 8 + m];   // w1[0][4m..4m+4)
    float4 w1f1 = ((const float4*)w1)[1 * 8 + m];
    float4 w1f2 = ((const float4*)w1)[2 * 8 + m];
    float4 b1f  = ((const float4*)b1)[m];
    float4 b2f  = ((const float4*)b2)[m];
    v2f w1_0A = {w1f0.x, w1f0.y}, w1_0B = {w1f0.z, w1f0.w};
    v2f w1_1A = {w1f1.x, w1f1.y}, w1_1B = {w1f1.z, w1f1.w};
    v2f w1_2A = {w1f2.x, w1f2.y}, w1_2B = {w1f2.z, w1f2.w};
    v2f b1A   = {b1f.x,  b1f.y }, b1B   = {b1f.z,  b1f.w };
    v2f b2A   = {b2f.x,  b2f.y }, b2B   = {b2f.z,  b2f.w };
    const v2f* w3v = (const v2f*)w3;               // row r = (w3[r][0], w3[r][1])
    v2f w3r0 = w3v[4*m+0], w3r1 = w3v[4*m+1], w3r2 = w3v[4*m+2], w3r3 = w3v[4*m+3];
    v2f b3c  = { b3[0], b3[1] };

    // Pin in VGPRs (round-3 evidence: prevents in-loop rematerialization).
#pragma unroll
    for (int k = 0; k < 16; ++k) {
        asm volatile("" : "+v"(w2mA[k]), "+v"(w2mB[k]), "+v"(w2oA[k]), "+v"(w2oB[k]));
    }
    asm volatile("" : "+v"(w1_0A), "+v"(w1_0B), "+v"(w1_1A), "+v"(w1_1B));
    asm volatile("" : "+v"(w1_2A), "+v"(w1_2B), "+v"(b1A), "+v"(b1B));
    asm volatile("" : "+v"(b2A), "+v"(b2B));
    asm volatile("" : "+v"(w3r0), "+v"(w3r1), "+v"(w3r2), "+v"(w3r3));

    v2f y = ((const v2f*)x)[elem];       // ODE state (y0, y1)
    float T = fminf(samples[elem], 50.0f);
    float t = 0.0f;
    float h = 0.05f;

    // f(t, y) -> v2f, cooperative across the 8-lane group
    auto f_eval = [&](float tt, v2f z) -> v2f {
        // layer 1: own 4 cols (2 packed pairs), relu
        v2f hA = vrelu(vfma(splat(tt), w1_0A, vfma(splat(z.x), w1_1A, vfma(splat(z.y), w1_2A, b1A))));
        v2f hB = vrelu(vfma(splat(tt), w1_0B, vfma(splat(z.x), w1_1B, vfma(splat(z.y), w1_2B, b1B))));

        // publish own 4 cols to LDS (for the other quad); same-wave DS is ordered
        float4 wv; wv.x = hA.x; wv.y = hA.y; wv.z = hB.x; wv.w = hB.y;
        ((float4*)slot)[m] = wv;

        // own-quad 16 cols via quad_perm DPP broadcasts (VALU pipe)
        float mg0  = dppf<0x00>(hA.x), mg1  = dppf<0x00>(hA.y),
              mg2  = dppf<0x00>(hB.x), mg3  = dppf<0x00>(hB.y);
        float mg4  = dppf<0x55>(hA.x), mg5  = dppf<0x55>(hA.y),
              mg6  = dppf<0x55>(hB.x), mg7  = dppf<0x55>(hB.y);
        float mg8  = dppf<0xAA>(hA.x), mg9  = dppf<0xAA>(hA.y),
              mg10 = dppf<0xAA>(hB.x), mg11 = dppf<0xAA>(hB.y);
        float mg12 = dppf<0xFF>(hA.x), mg13 = dppf<0xFF>(hA.y),
              mg14 = dppf<0xFF>(hB.x), mg15 = dppf<0xFF>(hB.y);

        // other-quad 16 cols: 4 broadcast b128 reads
        const float4* op = (const float4*)(slot + otherBase);
        float4 o0 = op[0], o1 = op[1], o2 = op[2], o3 = op[3];

        // layer 2: 4 independent packed chains (mine->aA/aB, other->cA/cB)
        v2f aA = b2A, aB = b2B, cA = splat(0.0f), cB = splat(0.0f);
        aA = vfma(splat(mg0 ), w2mA[ 0], aA); aB = vfma(splat(mg0 ), w2mB[ 0], aB);
        aA = vfma(splat(mg1 ), w2mA[ 1], aA); aB = vfma(splat(mg1 ), w2mB[ 1], aB);
        aA = vfma(splat(mg2 ), w2mA[ 2], aA); aB = vfma(splat(mg2 ), w2mB[ 2], aB);
        aA = vfma(splat(mg3 ), w2mA[ 3], aA); aB = vfma(splat(mg3 ), w2mB[ 3], aB);
        aA = vfma(splat(mg4 ), w2mA[ 4], aA); aB = vfma(splat(mg4 ), w2mB[ 4], aB);
        aA = vfma(splat(mg5 ), w2mA[ 5], aA); aB = vfma(splat(mg5 ), w2mB[ 5], aB);
        aA = vfma(splat(mg6 ), w2mA[ 6], aA); aB = vfma(splat(mg6 ), w2mB[ 6], aB);
        aA = vfma(splat(mg7 ), w2mA[ 7], aA); aB = vfma(splat(mg7 ), w2mB[ 7], aB);
        aA = vfma(splat(mg8 ), w2mA[ 8], aA); aB = vfma(splat(mg8 ), w2mB[ 8], aB);
        aA = vfma(splat(mg9 ), w2mA[ 9], aA); aB = vfma(splat(mg9 ), w2mB[ 9], aB);
        aA = vfma(splat(mg10), w2mA[10], aA); aB = vfma(splat(mg10), w2mB[10], aB);
        aA = vfma(splat(mg11), w2mA[11], aA); aB = vfma(splat(mg11), w2mB[11], aB);
        aA = vfma(splat(mg12), w2mA[12], aA); aB = vfma(splat(mg12), w2mB[12], aB);
        aA = vfma(splat(mg13), w2mA[13], aA); aB = vfma(splat(mg13), w2mB[13], aB);
        aA = vfma(splat(mg14), w2mA[14], aA); aB = vfma(splat(mg14), w2mB[14], aB);
        aA = vfma(splat(mg15), w2mA[15], aA); aB = vfma(splat(mg15), w2mB[15], aB);
        cA = vfma(splat(o0.x), w2oA[ 0], cA); cB = vfma(splat(o0.x), w2oB[ 0], cB);
        cA = vfma(splat(o0.y), w2oA[ 1], cA); cB = vfma(splat(o0.y), w2oB[ 1], cB);
        cA = vfma(splat(o0.z), w2oA[ 2], cA); cB = vfma(splat(o0.z), w2oB[ 2], cB);
        cA = vfma(splat(o0.w), w2oA[ 3], cA); cB = vfma(splat(o0.w), w2oB[ 3], cB);
        cA = vfma(splat(o1.x), w2oA[ 4], cA); cB = vfma(splat(o1.x), w2oB[ 4], cB);
        cA = vfma(splat(o1.y), w2oA[ 5], cA); cB = vfma(splat(o1.y), w2oB[ 5], cB);
        cA = vfma(splat(o1.z), w2oA[ 6], cA); cB = vfma(splat(o1.z), w2oB[ 6], cB);
        cA = vfma(splat(o1.w), w2oA[ 7], cA); cB = vfma(splat(o1.w), w2oB[ 7], cB);
        cA = vfma(splat(o2.x), w2oA[ 8], cA); cB = vfma(splat(o2.x), w2oB[ 8], cB);
        cA = vfma(splat(o2.y), w2oA[ 9], cA); cB = vfma(splat(o2.y), w2oB[ 9], cB);
        cA = vfma(splat(o2.z), w2oA[10], cA); cB = vfma(splat(o2.z), w2oB[10], cB);
        cA = vfma(splat(o2.w), w2oA[11], cA); cB = vfma(splat(o2.w), w2oB[11], cB);
        cA = vfma(splat(o3.x), w2oA[12], cA); cB = vfma(splat(o3.x), w2oB[12], cB);
        cA = vfma(splat(o3.y), w2oA[13], cA); cB = vfma(splat(o3.y), w2oB[13], cB);
        cA = vfma(splat(o3.z), w2oA[14], cA); cB = vfma(splat(o3.z), w2oB[14], cB);
        cA = vfma(splat(o3.w), w2oA[15], cA); cB = vfma(splat(o3.w), w2oB[15], cB);

        v2f h2A = vrelu(aA + cA);            // own cols 4m, 4m+1
        v2f h2B = vrelu(aB + cB);            // own cols 4m+2, 4m+3

        // layer 3: own 4 rows -> 4 packed FMAs, then 8-lane DPP all-reduce
        v2f p = vfma(splat(h2A.x), w3r0,
                vfma(splat(h2A.y), w3r1,
                vfma(splat(h2B.x), w3r2, splat(h2B.y) * w3r3)));
        p = dpp_allreduce8(p);
        return p + b3c;
    };

    // FSAL: initial k1; thereafter k1 = accept ? k7 : k1 (bitwise exact).
    v2f k1 = f_eval(0.0f, y);

    for (int s = 0; s < MAXS; ++s) {
        float rem = T - t;
        if (!(rem > 1e-8f)) break;           // state frozen from here on
        float hs = fminf(h, rem);
        v2f hb = splat(hs);

        v2f k2 = f_eval(t + hs * 0.2f, vfma(hb, splat(0.2f) * k1, y));
        v2f k3 = f_eval(t + hs * 0.3f,
                 vfma(hb, vfma(splat((float)(3.0/40.0)), k1, splat((float)(9.0/40.0)) * k2), y));
        v2f k4 = f_eval(t + hs * 0.8f,
                 vfma(hb, vfma(splat((float)(44.0/45.0)), k1,
                          vfma(splat((float)(-56.0/15.0)), k2, splat((float)(32.0/9.0)) * k3)), y));
        v2f k5 = f_eval(t + hs * (float)(8.0/9.0),
                 vfma(hb, vfma(splat((float)(19372.0/6561.0)), k1,
                          vfma(splat((float)(-25360.0/2187.0)), k2,
                          vfma(splat((float)(64448.0/6561.0)), k3,
                               splat((float)(-212.0/729.0)) * k4))), y));
        v2f k6 = f_eval(t + hs,
                 vfma(hb, vfma(splat((float)(9017.0/3168.0)), k1,
                          vfma(splat((float)(-355.0/33.0)), k2,
                          vfma(splat((float)(46732.0/5247.0)), k3,
                          vfma(splat((float)(49.0/176.0)), k4,
                               splat((float)(-5103.0/18656.0)) * k5)))), y));
        v2f y5 = vfma(hb, vfma(splat((float)(35.0/384.0)), k1,
                          vfma(splat((float)(500.0/1113.0)), k3,
                          vfma(splat((float)(125.0/192.0)), k4,
                          vfma(splat((float)(-2187.0/6784.0)), k5,
                               splat((float)(11.0/84.0)) * k6)))), y);
        v2f k7 = f_eval(t + hs, y5);

        v2f err = hb * vfma(splat((float)(71.0/57600.0)), k1,
                       vfma(splat((float)(-71.0/16695.0)), k3,
                       vfma(splat((float)(71.0/1920.0)), k4,
                       vfma(splat((float)(-17253.0/339200.0)), k5,
                       vfma(splat((float)(22.0/525.0)), k6,
                            splat((float)(-1.0/40.0)) * k7)))));

        v2f sc = vfma(splat(0.01f),
                 __builtin_elementwise_max(__builtin_elementwise_abs(y),
                                           __builtin_elementwise_abs(y5)), splat(0.01f));
        v2f r = err / sc;
        float en = sqrtf(0.5f * (r.x * r.x + r.y * r.y));

        float fac = fminf(fmaxf(0.9f * exp2f(-0.2f * log2f(fmaxf(en, 1e-10f))), 0.2f), 10.0f);

        bool accept = (en <= 1.0f);
        if (accept) { t += hs; y = y5; }
        k1 = accept ? k7 : k1;               // FSAL (exact)
        h = hs * fac;
    }

    // final head: y @ fc_w (2x10) + fc_b; all 8 lanes hold identical y.
    out[10 * elem + m] = fmaf(y.x, fcw[m], fmaf(y.y, fcw[10 + m], fcb[m]));
    if (m < 2) {
        int c = 8 + m;
        out[10 * elem + c] = fmaf(y.x, fcw[c], fmaf(y.y, fcw[10 + c], fcb[c]));
    }
}

extern "C" void kernel_launch(void* const* d_in, const int* in_sizes, int n_in,
                              void* d_out, int out_size, void* d_ws, size_t ws_size,
                              hipStream_t stream) {
    const float* x   = (const float*)d_in[0];
    const float* sm  = (const float*)d_in[1];
    const float* w1  = (const float*)d_in[2];
    const float* b1  = (const float*)d_in[3];
    const float* w2  = (const float*)d_in[4];
    const float* b2  = (const float*)d_in[5];
    const float* w3  = (const float*)d_in[6];
    const float* b3  = (const float*)d_in[7];
    const float* fcw = (const float*)d_in[8];
    const float* fcb = (const float*)d_in[9];
    // d_in[10..15] = enc_* : dead code in the reference, unused.
    float* out = (float*)d_out;

    int n = in_sizes[1];                        // B
    const int block = 256;                      // 32 groups/block
    long long threads = (long long)n * 8;       // 8 lanes per element
    int grid = (int)((threads + block - 1) / block);   // 512 blocks
    node_kernel<<<grid, block, 0, stream>>>(x, sm, w1, b1, w2, b2, w3, b3,
                                            fcw, fcb, out, n);
}